// Round 13
// baseline (2118.589 us; speedup 1.0000x reference)
//
#include <hip/hip_runtime.h>
#include <cstdint>
#include <cstddef>

#define BATCH 8
#define SEQ   256
#define HID   1024
#define GATES 4096   // 4*HID
#define VOC   32000

typedef __attribute__((ext_vector_type(8))) short bf16x8;
typedef __attribute__((ext_vector_type(4))) float f32x4;

// ---------- helpers ----------
__device__ __forceinline__ float sigf(float x){ return 1.0f/(1.0f + __expf(-x)); }
__device__ __forceinline__ float tanhf_(float x){ return 1.0f - 2.0f/(__expf(2.0f*x) + 1.0f); }

__device__ __forceinline__ unsigned short f2bf(float x){
  union { float f; unsigned u; } v; v.f = x;
  unsigned r = v.u + 0x7fffu + ((v.u >> 16) & 1u);
  return (unsigned short)(r >> 16);
}
__device__ __forceinline__ float bf2f(unsigned short h){
  union { float f; unsigned u; } v; v.u = ((unsigned)h) << 16; return v.f;
}

// ---------- init: zero epoch flags + packed h buffers ----------
__global__ void k_init(unsigned* __restrict__ flags, unsigned* __restrict__ hbu){
  int tid = blockIdx.x*blockDim.x + threadIdx.x;
  int nt = gridDim.x*blockDim.x;
  for (int i = tid; i < 256*16; i += nt) flags[i] = 0u;
  for (int i = tid; i < 16384; i += nt) hbu[i] = 0u;
}

// ---------- Wd -> bf16 hi/lo split (one-shot pre-pass) ----------
__global__ void k_wconv(const float* __restrict__ W,
                        unsigned short* __restrict__ WH,
                        unsigned short* __restrict__ WL){
  const int total4 = (HID*VOC) >> 2;   // 8.192M float4s
  int stride = gridDim.x*blockDim.x;
  for (int i = blockIdx.x*blockDim.x + threadIdx.x; i < total4; i += stride){
    float4 v = *(const float4*)(W + (size_t)i*4);
    float xs[4] = {v.x, v.y, v.z, v.w};
    unsigned hh = 0, ll = 0;
    #pragma unroll
    for (int c=0;c<4;c++){
      unsigned short h = f2bf(xs[c]);
      unsigned short lo = f2bf(xs[c] - bf2f(h));
      hh |= ((unsigned)h)  << (16*(c&1));
      ll |= ((unsigned)lo) << (16*(c&1));
      if (c==1){ ((unsigned*)&WH[(size_t)i*4])[0] = hh; ((unsigned*)&WL[(size_t)i*4])[0] = ll; hh=0; ll=0; }
      if (c==3){ ((unsigned*)&WH[(size_t)i*4])[1] = hh; ((unsigned*)&WL[(size_t)i*4])[1] = ll; }
    }
  }
}

// ---------- split-bf16 MFMA GEMM (R8/R10-validated) — used for G0 only ----------
template<int AMODE, int OMODE>
__global__ __launch_bounds__(256) void k_mfma(
    const float* __restrict__ A,
    const float* __restrict__ W,     // [1024][N]
    const float* __restrict__ b1,
    const float* __restrict__ b2,
    const int*   __restrict__ tokens,
    const float* __restrict__ emb,
    float* __restrict__ C, int N)
{
  __shared__ unsigned short AsH[16*1024], AsL[16*1024];
  __shared__ unsigned short BsH[8*1024],  BsL[8*1024];
  int tid = threadIdx.x;
  int m0 = blockIdx.y*256, n0 = blockIdx.x*128;
  int w = tid >> 6, l = tid & 63;
  int lrow = l & 15, kg = l >> 4;

  f32x4 acc[4][8];
  #pragma unroll
  for (int i=0;i<4;i++){
    #pragma unroll
    for (int j=0;j<8;j++) acc[i][j] = (f32x4){0.f,0.f,0.f,0.f};
  }

  int rA  = tid >> 3, fq = tid & 7;

  const float* arow[8];
  #pragma unroll
  for (int i=0;i<8;i++){
    int gm = m0 + rA + 32*i;
    if (AMODE==1) arow[i] = emb + (size_t)tokens[(gm&7)*SEQ + (gm>>3)]*1024;
    else          arow[i] = A   + (size_t)gm*1024;
  }

  for (int kt=0; kt<32; ++kt){
    int k0 = kt*32;
    float4 av[8];
    #pragma unroll
    for (int i=0;i<8;i++)
      av[i] = *(const float4*)(arow[i] + k0 + fq*4);
    float4 wv[4];
    #pragma unroll
    for (int i=0;i<4;i++)
      wv[i] = *(const float4*)(W + (size_t)(k0 + rA)*N + n0 + fq*4 + 32*i);
    __syncthreads();
    #pragma unroll
    for (int i=0;i<8;i++){
      int r = rA + 32*i;
      int base = (r >> 4)*1024 + ((fq >> 1)*16 + (r & 15))*8 + (fq & 1)*4;
      float xs[4] = {av[i].x, av[i].y, av[i].z, av[i].w};
      unsigned long long ph = 0ull, pl = 0ull;
      #pragma unroll
      for (int c=0;c<4;c++){
        unsigned short h = f2bf(xs[c]);
        unsigned short lo = f2bf(xs[c] - bf2f(h));
        ph |= ((unsigned long long)h) << (16*c);
        pl |= ((unsigned long long)lo) << (16*c);
      }
      *(unsigned long long*)&AsH[base] = ph;
      *(unsigned long long*)&AsL[base] = pl;
    }
    #pragma unroll
    for (int i=0;i<4;i++){
      float xs[4] = {wv[i].x, wv[i].y, wv[i].z, wv[i].w};
      #pragma unroll
      for (int c=0;c<4;c++){
        int col = fq*4 + 32*i + c;
        int idx = (col >> 4)*1024 + ((rA >> 3)*16 + (col & 15))*8 + (rA & 7);
        unsigned short h = f2bf(xs[c]);
        BsH[idx] = h;
        BsL[idx] = f2bf(xs[c] - bf2f(h));
      }
    }
    __syncthreads();
    bf16x8 ah[4], al[4];
    #pragma unroll
    for (int i=0;i<4;i++){
      int fi = w*4 + i;
      ah[i] = *(const bf16x8*)&AsH[fi*1024 + l*8];
      al[i] = *(const bf16x8*)&AsL[fi*1024 + l*8];
    }
    #pragma unroll
    for (int jh=0;jh<2;jh++){
      bf16x8 bh_[4], bl_[4];
      #pragma unroll
      for (int j=0;j<4;j++){
        bh_[j] = *(const bf16x8*)&BsH[(jh*4+j)*1024 + l*8];
        bl_[j] = *(const bf16x8*)&BsL[(jh*4+j)*1024 + l*8];
      }
      #pragma unroll
      for (int i=0;i<4;i++){
        #pragma unroll
        for (int j=0;j<4;j++){
          f32x4 a = acc[i][jh*4+j];
          a = __builtin_amdgcn_mfma_f32_16x16x32_bf16(ah[i], bh_[j], a, 0,0,0);
          a = __builtin_amdgcn_mfma_f32_16x16x32_bf16(ah[i], bl_[j], a, 0,0,0);
          a = __builtin_amdgcn_mfma_f32_16x16x32_bf16(al[i], bh_[j], a, 0,0,0);
          acc[i][jh*4+j] = a;
        }
      }
    }
    __syncthreads();
  }

  int mbase = m0 + w*64 + kg*4;
  #pragma unroll
  for (int jj=0;jj<8;jj++){
    int gn = n0 + jj*16 + lrow;
    float bias = b1[gn];
    if (b2) bias += b2[gn];
    #pragma unroll
    for (int i=0;i<4;i++){
      #pragma unroll
      for (int r=0;r<4;r++){
        int m = mbase + i*16 + r;
        size_t crow = (OMODE==1) ? (size_t)((m & 7)*SEQ + (m >> 3)) : (size_t)m;
        C[crow*(size_t)N + gn] = acc[i][jj][r] + bias;
      }
    }
  }
}

// ---------- final projection: pre-split A (and W if WPRE) -> bit-copy staging ----------
// out[(m&7)*SEQ + (m>>3)][n] = TopsRow(m) @ Wd + bd, 3-pass split-bf16 MFMA.
template<int WPRE>
__global__ __launch_bounds__(256) void k_proj(
    const unsigned short* __restrict__ AH,  // TopsH [2048][1024]
    const unsigned short* __restrict__ AL,  // TopsL
    const float* __restrict__ Wf,           // Wd f32 (WPRE=0)
    const unsigned short* __restrict__ WH,  // WdH   (WPRE=1)
    const unsigned short* __restrict__ WL,  // WdL
    const float* __restrict__ bd,
    float* __restrict__ C)
{
  __shared__ unsigned short AsH[16*1024], AsL[16*1024];
  __shared__ unsigned short BsH[8*1024],  BsL[8*1024];
  int tid = threadIdx.x;
  int m0 = blockIdx.y*256, n0 = blockIdx.x*128;
  int w = tid >> 6, l = tid & 63;
  int lrow = l & 15, kg = l >> 4;

  f32x4 acc[4][8];
  #pragma unroll
  for (int i=0;i<4;i++){
    #pragma unroll
    for (int j=0;j<8;j++) acc[i][j] = (f32x4){0.f,0.f,0.f,0.f};
  }

  int rA = tid >> 3, fq = tid & 7;

  for (int kt=0; kt<32; ++kt){
    int k0 = kt*32;
    // A: 8 rows x 4 bf16 (8B) each, straight from pre-split arrays
    uint2 avh[8], avl[8];
    #pragma unroll
    for (int i=0;i<8;i++){
      size_t off = (size_t)(m0 + rA + 32*i)*1024 + k0 + fq*4;
      avh[i] = *(const uint2*)&AH[off];
      avl[i] = *(const uint2*)&AL[off];
    }
    // W: 4 x (4 cols at one k)
    uint2 wvh[4], wvl[4];
    float4 wvf[4];
    #pragma unroll
    for (int i=0;i<4;i++){
      size_t off = (size_t)(k0 + rA)*VOC + n0 + fq*4 + 32*i;
      if (WPRE){ wvh[i] = *(const uint2*)&WH[off]; wvl[i] = *(const uint2*)&WL[off]; }
      else     { wvf[i] = *(const float4*)(Wf + off); }
    }
    __syncthreads();
    // A staging: pure 8B bit-copies
    #pragma unroll
    for (int i=0;i<8;i++){
      int r = rA + 32*i;
      int base = (r >> 4)*1024 + ((fq >> 1)*16 + (r & 15))*8 + (fq & 1)*4;
      *(uint2*)&AsH[base] = avh[i];
      *(uint2*)&AsL[base] = avl[i];
    }
    // B staging: scatter 4 u16 per quad
    #pragma unroll
    for (int i=0;i<4;i++){
      #pragma unroll
      for (int c=0;c<4;c++){
        int col = fq*4 + 32*i + c;
        int idx = (col >> 4)*1024 + ((rA >> 3)*16 + (col & 15))*8 + (rA & 7);
        if (WPRE){
          BsH[idx] = ((const unsigned short*)&wvh[i])[c];
          BsL[idx] = ((const unsigned short*)&wvl[i])[c];
        } else {
          float xs = (c==0)?wvf[i].x:(c==1)?wvf[i].y:(c==2)?wvf[i].z:wvf[i].w;
          unsigned short h = f2bf(xs);
          BsH[idx] = h;
          BsL[idx] = f2bf(xs - bf2f(h));
        }
      }
    }
    __syncthreads();
    bf16x8 ah[4], al[4];
    #pragma unroll
    for (int i=0;i<4;i++){
      int fi = w*4 + i;
      ah[i] = *(const bf16x8*)&AsH[fi*1024 + l*8];
      al[i] = *(const bf16x8*)&AsL[fi*1024 + l*8];
    }
    #pragma unroll
    for (int jh=0;jh<2;jh++){
      bf16x8 bh_[4], bl_[4];
      #pragma unroll
      for (int j=0;j<4;j++){
        bh_[j] = *(const bf16x8*)&BsH[(jh*4+j)*1024 + l*8];
        bl_[j] = *(const bf16x8*)&BsL[(jh*4+j)*1024 + l*8];
      }
      #pragma unroll
      for (int i=0;i<4;i++){
        #pragma unroll
        for (int j=0;j<4;j++){
          f32x4 a = acc[i][jh*4+j];
          a = __builtin_amdgcn_mfma_f32_16x16x32_bf16(ah[i], bh_[j], a, 0,0,0);
          a = __builtin_amdgcn_mfma_f32_16x16x32_bf16(ah[i], bl_[j], a, 0,0,0);
          a = __builtin_amdgcn_mfma_f32_16x16x32_bf16(al[i], bh_[j], a, 0,0,0);
          acc[i][jh*4+j] = a;
        }
      }
    }
    __syncthreads();
  }

  int mbase = m0 + w*64 + kg*4;
  #pragma unroll
  for (int jj=0;jj<8;jj++){
    int gn = n0 + jj*16 + lrow;
    float bias = bd[gn];
    #pragma unroll
    for (int i=0;i<4;i++){
      #pragma unroll
      for (int r=0;r<4;r++){
        int m = mbase + i*16 + r;
        size_t crow = (size_t)((m & 7)*SEQ + (m >> 3));
        C[crow*(size_t)VOC + gn] = acc[i][jj][r] + bias;
      }
    }
  }
}

// ---------- fused 2-layer pipelined recurrence (v10 + bf16 Tops output) ----------
__global__ __launch_bounds__(256) void k_rec2(
    const float* __restrict__ G,      // G0 [2048][4096], bias folded
    const float* __restrict__ Wh,     // [2][1024][4096]
    const float* __restrict__ Wx,     // [2][1024][4096]
    const float* __restrict__ bx1,    // bx + GATES
    const float* __restrict__ bh1,    // bh + GATES
    unsigned short* __restrict__ TopsH,  // [2048][1024] bf16 hi, row = s*8+b
    unsigned short* __restrict__ TopsL,  // bf16 lo
    unsigned* __restrict__ hbu,       // packed h [2 layers][2 parity][8][512]
    unsigned* __restrict__ flags)     // [256][16]
{
  extern __shared__ char ldsb[];
  unsigned short* A0 = (unsigned short*)ldsb;
  unsigned short* A1 = A0 + 16384;
  unsigned short* A2 = A1 + 16384;
  unsigned short* hB = A2 + 16384;
  float* Cx = (float*)(ldsb + 131072);
  int tid = threadIdx.x;
  int u0 = blockIdx.x*4;
  const int wv = tid >> 6, ln = tid & 63;
  const int fs0 = tid*16, fs1 = (tid+64)*16, fs2 = (tid+128)*16, fs3 = (tid+192)*16;

  // one-time: stage 3 weight A-tiles (bf16 frag-linear), strided reads
  {
    int m = tid >> 4, kseg = tid & 15;
    int col = (m >> 2)*1024 + u0 + (m & 3);
    const float* wsrc[3] = { Wh, Wx + (size_t)HID*GATES, Wh + (size_t)HID*GATES };
    unsigned short* Ad[3] = { A0, A1, A2 };
    for (int tgt=0; tgt<3; ++tgt){
      const float* s = wsrc[tgt] + col;
      #pragma unroll
      for (int run=0; run<8; ++run){
        int k0 = kseg*64 + run*8;
        int kt = k0 >> 5, kg = (k0 >> 3) & 3;
        bf16x8 v;
        #pragma unroll
        for (int e=0;e<8;e++) v[e] = (short)f2bf(s[(size_t)(k0+e)*GATES]);
        *(bf16x8*)&Ad[tgt][kt*512 + ((kg<<4)|m)*8] = v;
      }
    }
  }
  float b1r[4] = {0.f,0.f,0.f,0.f};
  if (tid >= 32 && tid < 64){
    int j = tid & 3;
    #pragma unroll
    for (int g=0;g<4;g++) b1r[g] = bx1[g*1024+u0+j] + bh1[g*1024+u0+j];
  }
  float creg = 0.0f;

  for (int p=0; p<=SEQ; ++p){
    const unsigned* h0b = hbu + (size_t)(p&1)*4096;
    const unsigned* h1b = hbu + 8192 + (size_t)((p+1)&1)*4096;
    {
      int colp = tid & 15, seg0 = tid >> 4;
      #pragma unroll
      for (int i=0;i<2;i++){
        int seg = seg0 + 16*i;
        const float* src = (const float*)(((colp < 8) ? h0b : h1b)
                                          + (colp & 7)*512 + seg*16);
        float4 r0,r1,r2,r3;
        asm volatile(
          "global_load_dwordx4 %0, %4, off sc0 sc1\n\t"
          "global_load_dwordx4 %1, %4, off offset:16 sc0 sc1\n\t"
          "global_load_dwordx4 %2, %4, off offset:32 sc0 sc1\n\t"
          "global_load_dwordx4 %3, %4, off offset:48 sc0 sc1\n\t"
          "s_waitcnt vmcnt(0)"
          : "=&v"(r0),"=&v"(r1),"=&v"(r2),"=&v"(r3)
          : "v"(src)
          : "memory");
        *(float4*)&hB[seg*512 + ((0<<4)|colp)*8] = r0;
        *(float4*)&hB[seg*512 + ((1<<4)|colp)*8] = r1;
        *(float4*)&hB[seg*512 + ((2<<4)|colp)*8] = r2;
        *(float4*)&hB[seg*512 + ((3<<4)|colp)*8] = r3;
      }
    }
    float gp0=0.f,gp1=0.f,gp2=0.f,gp3=0.f;
    if (tid < 32 && p < SEQ){
      const float* gp = G + ((size_t)p*8 + (tid>>2))*GATES + u0 + (tid&3);
      gp0 = gp[0]; gp1 = gp[1024]; gp2 = gp[2048]; gp3 = gp[3072];
    }
    __syncthreads();

    f32x4 C0 = {0.f,0.f,0.f,0.f}, C1 = {0.f,0.f,0.f,0.f}, C2 = {0.f,0.f,0.f,0.f};
    #pragma unroll
    for (int kti=0; kti<8; ++kti){
      int kt = wv + kti*4;
      bf16x8 bB = *(const bf16x8*)&hB[kt*512 + ln*8];
      bf16x8 a0 = *(const bf16x8*)&A0[kt*512 + ln*8];
      bf16x8 a1 = *(const bf16x8*)&A1[kt*512 + ln*8];
      bf16x8 a2 = *(const bf16x8*)&A2[kt*512 + ln*8];
      C0 = __builtin_amdgcn_mfma_f32_16x16x32_bf16(a0, bB, C0, 0,0,0);
      C1 = __builtin_amdgcn_mfma_f32_16x16x32_bf16(a1, bB, C1, 0,0,0);
      C2 = __builtin_amdgcn_mfma_f32_16x16x32_bf16(a2, bB, C2, 0,0,0);
    }
    {
      int cn = ln & 15, mb = (ln >> 4)*4;
      #pragma unroll
      for (int r=0;r<4;r++){
        Cx[((wv*3+0)*16 + mb+r)*17 + cn] = C0[r];
        Cx[((wv*3+1)*16 + mb+r)*17 + cn] = C1[r];
        Cx[((wv*3+2)*16 + mb+r)*17 + cn] = C2[r];
      }
    }
    __syncthreads();

    float hv = 0.f; bool pub = false; unsigned dstbase = 0;
    if (tid < 32){
      if (p < SEQ){
        int b = tid >> 2, j = tid & 3;
        float gv0=gp0, gv1=gp1, gv2=gp2, gv3=gp3;
        #pragma unroll
        for (int w=0;w<4;w++){
          gv0 += Cx[((w*3+0)*16 + 0*4+j)*17 + b];
          gv1 += Cx[((w*3+0)*16 + 1*4+j)*17 + b];
          gv2 += Cx[((w*3+0)*16 + 2*4+j)*17 + b];
          gv3 += Cx[((w*3+0)*16 + 3*4+j)*17 + b];
        }
        float iv = sigf(gv0), fv = sigf(gv1), ov = sigf(gv3), gg = tanhf_(gv2);
        creg = fv*creg + iv*gg;
        hv = ov * tanhf_(creg);
        pub = true; dstbase = ((unsigned)(p+1)&1u)*4096u;
      }
    } else if (tid < 64){
      if (p > 0){
        int b = (tid-32) >> 2, j = tid & 3;
        float gv0=b1r[0], gv1=b1r[1], gv2=b1r[2], gv3=b1r[3];
        #pragma unroll
        for (int w=0;w<4;w++){
          gv0 += Cx[((w*3+1)*16 + 0*4+j)*17 + b] + Cx[((w*3+2)*16 + 0*4+j)*17 + b+8];
          gv1 += Cx[((w*3+1)*16 + 1*4+j)*17 + b] + Cx[((w*3+2)*16 + 1*4+j)*17 + b+8];
          gv2 += Cx[((w*3+1)*16 + 2*4+j)*17 + b] + Cx[((w*3+2)*16 + 2*4+j)*17 + b+8];
          gv3 += Cx[((w*3+1)*16 + 3*4+j)*17 + b] + Cx[((w*3+2)*16 + 3*4+j)*17 + b+8];
        }
        float iv = sigf(gv0), fv = sigf(gv1), ov = sigf(gv3), gg = tanhf_(gv2);
        creg = fv*creg + iv*gg;
        hv = ov * tanhf_(creg);
        pub = true; dstbase = 8192u + ((unsigned)p&1u)*4096u;
        // Tops emitted pre-split as bf16 hi/lo (same bits k_proj would compute)
        unsigned short hi = f2bf(hv);
        unsigned short lo = f2bf(hv - bf2f(hi));
        size_t off = ((size_t)(p-1)*8 + b)*HID + u0 + (tid&3);
        TopsH[off] = hi;
        TopsL[off] = lo;
      }
    }
    if (tid < 64){
      unsigned mybits = (unsigned)f2bf(hv);
      unsigned other  = (unsigned)__shfl_xor((int)mybits, 1);
      if (pub && ((tid & 1) == 0)){
        unsigned word = (mybits & 0xffffu) | (other << 16);
        int b = (tid & 31) >> 2;
        int widx = (u0 >> 1) + ((tid >> 1) & 1);
        (void)__hip_atomic_exchange(&hbu[dstbase + b*512 + widx], word,
                                    __ATOMIC_RELAXED, __HIP_MEMORY_SCOPE_AGENT);
      }
    }

    if (p < SEQ){
      if (tid < 64){
        if (tid == 0){
          asm volatile("s_waitcnt vmcnt(0)" ::: "memory");
          (void)__hip_atomic_exchange(&flags[blockIdx.x*16], (unsigned)(p+1),
                                      __ATOMIC_RELAXED, __HIP_MEMORY_SCOPE_AGENT);
        }
        unsigned tgt = (unsigned)(p+1);
        int spins = 0;
        for (;;){
          unsigned a = __hip_atomic_load(&flags[fs0], __ATOMIC_RELAXED, __HIP_MEMORY_SCOPE_AGENT);
          unsigned b = __hip_atomic_load(&flags[fs1], __ATOMIC_RELAXED, __HIP_MEMORY_SCOPE_AGENT);
          unsigned c = __hip_atomic_load(&flags[fs2], __ATOMIC_RELAXED, __HIP_MEMORY_SCOPE_AGENT);
          unsigned d = __hip_atomic_load(&flags[fs3], __ATOMIC_RELAXED, __HIP_MEMORY_SCOPE_AGENT);
          bool ok = (a >= tgt) && (b >= tgt) && (c >= tgt) && (d >= tgt);
          if (__all(ok)) break;
          __builtin_amdgcn_s_sleep(1);
          if (++spins > 150000){
            for (;;){
              unsigned a2 = __hip_atomic_load(&flags[fs0], __ATOMIC_ACQUIRE, __HIP_MEMORY_SCOPE_AGENT);
              unsigned b2 = __hip_atomic_load(&flags[fs1], __ATOMIC_ACQUIRE, __HIP_MEMORY_SCOPE_AGENT);
              unsigned c2 = __hip_atomic_load(&flags[fs2], __ATOMIC_ACQUIRE, __HIP_MEMORY_SCOPE_AGENT);
              unsigned d2 = __hip_atomic_load(&flags[fs3], __ATOMIC_ACQUIRE, __HIP_MEMORY_SCOPE_AGENT);
              bool ok2 = (a2 >= tgt) && (b2 >= tgt) && (c2 >= tgt) && (d2 >= tgt);
              if (__all(ok2)) break;
              __builtin_amdgcn_s_sleep(8);
              if (++spins > 8000000) break;   // wrong answer beats a hang
            }
            break;
          }
        }
      }
      __syncthreads();
    }
  }
}

extern "C" void kernel_launch(void* const* d_in, const int* in_sizes, int n_in,
                              void* d_out, int out_size, void* d_ws, size_t ws_size,
                              hipStream_t stream) {
  const int*   tokens = (const int*)d_in[0];
  const float* emb = (const float*)d_in[1];
  const float* Wx  = (const float*)d_in[2];
  const float* bx  = (const float*)d_in[3];
  const float* Wh  = (const float*)d_in[4];
  const float* bh  = (const float*)d_in[5];
  const float* Wd  = (const float*)d_in[6];
  const float* bd  = (const float*)d_in[7];
  float* out = (float*)d_out;
  float* ws  = (float*)d_ws;

  // ws layout (float offsets):
  //   G 0..8388608 | TopsH 8388608 | TopsL 9437184 | hbu 10485760 |
  //   flags 10502144 | WdH 10506240 | WdL 26890240 | end 43274240
  float* G = ws;
  unsigned short* TopsH = (unsigned short*)(ws + (size_t)8388608);
  unsigned short* TopsL = (unsigned short*)(ws + (size_t)9437184);
  unsigned* hbu   = (unsigned*)(ws + (size_t)10485760);
  unsigned* flags = (unsigned*)(ws + (size_t)10502144);
  unsigned short* WdH = (unsigned short*)(ws + (size_t)10506240);
  unsigned short* WdL = (unsigned short*)(ws + (size_t)26890240);
  const bool wpre = ws_size >= (size_t)43274240*4;

  (void)hipFuncSetAttribute((const void*)k_rec2,
        hipFuncAttributeMaxDynamicSharedMemorySize, 144128);

  k_init<<<32,256,0,stream>>>(flags, hbu);
  if (wpre)
    k_wconv<<<2048,256,0,stream>>>(Wd, WdH, WdL);

  // G0 = emb[tok] @ Wx0 + (bx0+bh0)   [split-bf16 MFMA]
  k_mfma<1,0><<<dim3(32,8),256,0,stream>>>(nullptr, Wx, bx, bh, tokens, emb, G, GATES);

  // fused pipelined recurrence: both layers, 257 phases
  k_rec2<<<256,256,144128,stream>>>(G, Wh, Wx, bx + GATES, bh + GATES,
                                    TopsH, TopsL, hbu, flags);

  // final projection
  if (wpre)
    k_proj<1><<<dim3(250,8),256,0,stream>>>(TopsH, TopsL, nullptr, WdH, WdL, bd, out);
  else
    k_proj<0><<<dim3(250,8),256,0,stream>>>(TopsH, TopsL, Wd, nullptr, nullptr, bd, out);
}

// Round 14
// 1737.664 us; speedup vs baseline: 1.2192x; 1.2192x over previous
//
#include <hip/hip_runtime.h>
#include <cstdint>
#include <cstddef>

#define BATCH 8
#define SEQ   256
#define HID   1024
#define GATES 4096   // 4*HID
#define VOC   32000

typedef __attribute__((ext_vector_type(8))) short bf16x8;
typedef __attribute__((ext_vector_type(4))) float f32x4;

// ---------- helpers ----------
__device__ __forceinline__ float sigf(float x){ return 1.0f/(1.0f + __expf(-x)); }
__device__ __forceinline__ float tanhf_(float x){ return 1.0f - 2.0f/(__expf(2.0f*x) + 1.0f); }

__device__ __forceinline__ unsigned short f2bf(float x){
  union { float f; unsigned u; } v; v.f = x;
  unsigned r = v.u + 0x7fffu + ((v.u >> 16) & 1u);
  return (unsigned short)(r >> 16);
}
__device__ __forceinline__ float bf2f(unsigned short h){
  union { float f; unsigned u; } v; v.u = ((unsigned)h) << 16; return v.f;
}

// ---------- init: zero epoch flags + packed h buffers ----------
__global__ void k_init(unsigned* __restrict__ flags, unsigned* __restrict__ hbu){
  int tid = blockIdx.x*blockDim.x + threadIdx.x;
  int nt = gridDim.x*blockDim.x;
  for (int i = tid; i < 256*16; i += nt) flags[i] = 0u;
  for (int i = tid; i < 16384; i += nt) hbu[i] = 0u;
}

// ---------- Wd -> single-bf16 (hi only) pre-pass ----------
__global__ void k_wconv(const float* __restrict__ W,
                        unsigned short* __restrict__ WH){
  const int total4 = (HID*VOC) >> 2;
  int stride = gridDim.x*blockDim.x;
  for (int i = blockIdx.x*blockDim.x + threadIdx.x; i < total4; i += stride){
    float4 v = *(const float4*)(W + (size_t)i*4);
    uint2 o;
    o.x = ((unsigned)f2bf(v.x)) | (((unsigned)f2bf(v.y)) << 16);
    o.y = ((unsigned)f2bf(v.z)) | (((unsigned)f2bf(v.w)) << 16);
    *(uint2*)&WH[(size_t)i*4] = o;
  }
}

// ---------- split-bf16 MFMA GEMM (R8/R10-validated) — used for G0 only ----------
template<int AMODE, int OMODE>
__global__ __launch_bounds__(256) void k_mfma(
    const float* __restrict__ A,
    const float* __restrict__ W,     // [1024][N]
    const float* __restrict__ b1,
    const float* __restrict__ b2,
    const int*   __restrict__ tokens,
    const float* __restrict__ emb,
    float* __restrict__ C, int N)
{
  __shared__ unsigned short AsH[16*1024], AsL[16*1024];
  __shared__ unsigned short BsH[8*1024],  BsL[8*1024];
  int tid = threadIdx.x;
  int m0 = blockIdx.y*256, n0 = blockIdx.x*128;
  int w = tid >> 6, l = tid & 63;
  int lrow = l & 15, kg = l >> 4;

  f32x4 acc[4][8];
  #pragma unroll
  for (int i=0;i<4;i++){
    #pragma unroll
    for (int j=0;j<8;j++) acc[i][j] = (f32x4){0.f,0.f,0.f,0.f};
  }

  int rA  = tid >> 3, fq = tid & 7;

  const float* arow[8];
  #pragma unroll
  for (int i=0;i<8;i++){
    int gm = m0 + rA + 32*i;
    if (AMODE==1) arow[i] = emb + (size_t)tokens[(gm&7)*SEQ + (gm>>3)]*1024;
    else          arow[i] = A   + (size_t)gm*1024;
  }

  for (int kt=0; kt<32; ++kt){
    int k0 = kt*32;
    float4 av[8];
    #pragma unroll
    for (int i=0;i<8;i++)
      av[i] = *(const float4*)(arow[i] + k0 + fq*4);
    float4 wv[4];
    #pragma unroll
    for (int i=0;i<4;i++)
      wv[i] = *(const float4*)(W + (size_t)(k0 + rA)*N + n0 + fq*4 + 32*i);
    __syncthreads();
    #pragma unroll
    for (int i=0;i<8;i++){
      int r = rA + 32*i;
      int base = (r >> 4)*1024 + ((fq >> 1)*16 + (r & 15))*8 + (fq & 1)*4;
      float xs[4] = {av[i].x, av[i].y, av[i].z, av[i].w};
      unsigned long long ph = 0ull, pl = 0ull;
      #pragma unroll
      for (int c=0;c<4;c++){
        unsigned short h = f2bf(xs[c]);
        unsigned short lo = f2bf(xs[c] - bf2f(h));
        ph |= ((unsigned long long)h) << (16*c);
        pl |= ((unsigned long long)lo) << (16*c);
      }
      *(unsigned long long*)&AsH[base] = ph;
      *(unsigned long long*)&AsL[base] = pl;
    }
    #pragma unroll
    for (int i=0;i<4;i++){
      float xs[4] = {wv[i].x, wv[i].y, wv[i].z, wv[i].w};
      #pragma unroll
      for (int c=0;c<4;c++){
        int col = fq*4 + 32*i + c;
        int idx = (col >> 4)*1024 + ((rA >> 3)*16 + (col & 15))*8 + (rA & 7);
        unsigned short h = f2bf(xs[c]);
        BsH[idx] = h;
        BsL[idx] = f2bf(xs[c] - bf2f(h));
      }
    }
    __syncthreads();
    bf16x8 ah[4], al[4];
    #pragma unroll
    for (int i=0;i<4;i++){
      int fi = w*4 + i;
      ah[i] = *(const bf16x8*)&AsH[fi*1024 + l*8];
      al[i] = *(const bf16x8*)&AsL[fi*1024 + l*8];
    }
    #pragma unroll
    for (int jh=0;jh<2;jh++){
      bf16x8 bh_[4], bl_[4];
      #pragma unroll
      for (int j=0;j<4;j++){
        bh_[j] = *(const bf16x8*)&BsH[(jh*4+j)*1024 + l*8];
        bl_[j] = *(const bf16x8*)&BsL[(jh*4+j)*1024 + l*8];
      }
      #pragma unroll
      for (int i=0;i<4;i++){
        #pragma unroll
        for (int j=0;j<4;j++){
          f32x4 a = acc[i][jh*4+j];
          a = __builtin_amdgcn_mfma_f32_16x16x32_bf16(ah[i], bh_[j], a, 0,0,0);
          a = __builtin_amdgcn_mfma_f32_16x16x32_bf16(ah[i], bl_[j], a, 0,0,0);
          a = __builtin_amdgcn_mfma_f32_16x16x32_bf16(al[i], bh_[j], a, 0,0,0);
          acc[i][jh*4+j] = a;
        }
      }
    }
    __syncthreads();
  }

  int mbase = m0 + w*64 + kg*4;
  #pragma unroll
  for (int jj=0;jj<8;jj++){
    int gn = n0 + jj*16 + lrow;
    float bias = b1[gn];
    if (b2) bias += b2[gn];
    #pragma unroll
    for (int i=0;i<4;i++){
      #pragma unroll
      for (int r=0;r<4;r++){
        int m = mbase + i*16 + r;
        size_t crow = (OMODE==1) ? (size_t)((m & 7)*SEQ + (m >> 3)) : (size_t)m;
        C[crow*(size_t)N + gn] = acc[i][jj][r] + bias;
      }
    }
  }
}

// ---------- k_proj1: 2-pass projection with single-bf16 W, 80KB LDS (2 blk/CU),
//            register prefetch. out = (Ah + Al) @ Wh + bd ----------
__global__ __launch_bounds__(256,2) void k_proj1(
    const unsigned short* __restrict__ AH,  // TopsH [2048][1024]
    const unsigned short* __restrict__ AL,  // TopsL
    const unsigned short* __restrict__ WH,  // WdH [1024][32000] bf16
    const float* __restrict__ bd,
    float* __restrict__ C)
{
  __shared__ unsigned short AsH[16*1024], AsL[16*1024];  // 64 KB
  __shared__ unsigned short BsH[8*1024];                 // 16 KB -> 80 KB total
  int tid = threadIdx.x;
  int m0 = blockIdx.y*256, n0 = blockIdx.x*128;
  int w = tid >> 6, l = tid & 63;
  int lrow = l & 15, kg = l >> 4;

  f32x4 acc[4][8];
  #pragma unroll
  for (int i=0;i<4;i++){
    #pragma unroll
    for (int j=0;j<8;j++) acc[i][j] = (f32x4){0.f,0.f,0.f,0.f};
  }

  int rA = tid >> 3, fq = tid & 7;

  uint2 avh[8], avl[8], wvh[4];
  // prefetch iter 0
  #pragma unroll
  for (int i=0;i<8;i++){
    size_t off = (size_t)(m0 + rA + 32*i)*1024 + fq*4;
    avh[i] = *(const uint2*)&AH[off];
    avl[i] = *(const uint2*)&AL[off];
  }
  #pragma unroll
  for (int i=0;i<4;i++)
    wvh[i] = *(const uint2*)&WH[(size_t)rA*VOC + n0 + fq*4 + 32*i];

  for (int kt=0; kt<32; ++kt){
    __syncthreads();   // previous iter's MFMA done reading LDS
    // stage (pure bit-copies)
    #pragma unroll
    for (int i=0;i<8;i++){
      int r = rA + 32*i;
      int base = (r >> 4)*1024 + ((fq >> 1)*16 + (r & 15))*8 + (fq & 1)*4;
      *(uint2*)&AsH[base] = avh[i];
      *(uint2*)&AsL[base] = avl[i];
    }
    #pragma unroll
    for (int i=0;i<4;i++){
      #pragma unroll
      for (int c=0;c<4;c++){
        int col = fq*4 + 32*i + c;
        int idx = (col >> 4)*1024 + ((rA >> 3)*16 + (col & 15))*8 + (rA & 7);
        BsH[idx] = ((const unsigned short*)&wvh[i])[c];
      }
    }
    __syncthreads();
    // prefetch next iter while MFMAs run
    if (kt < 31){
      int k0 = (kt+1)*32;
      #pragma unroll
      for (int i=0;i<8;i++){
        size_t off = (size_t)(m0 + rA + 32*i)*1024 + k0 + fq*4;
        avh[i] = *(const uint2*)&AH[off];
        avl[i] = *(const uint2*)&AL[off];
      }
      #pragma unroll
      for (int i=0;i<4;i++)
        wvh[i] = *(const uint2*)&WH[(size_t)(k0 + rA)*VOC + n0 + fq*4 + 32*i];
    }
    // 2-pass MFMA
    bf16x8 ah[4], al[4];
    #pragma unroll
    for (int i=0;i<4;i++){
      int fi = w*4 + i;
      ah[i] = *(const bf16x8*)&AsH[fi*1024 + l*8];
      al[i] = *(const bf16x8*)&AsL[fi*1024 + l*8];
    }
    #pragma unroll
    for (int jh=0;jh<2;jh++){
      bf16x8 bh_[4];
      #pragma unroll
      for (int j=0;j<4;j++)
        bh_[j] = *(const bf16x8*)&BsH[(jh*4+j)*1024 + l*8];
      #pragma unroll
      for (int i=0;i<4;i++){
        #pragma unroll
        for (int j=0;j<4;j++){
          f32x4 a = acc[i][jh*4+j];
          a = __builtin_amdgcn_mfma_f32_16x16x32_bf16(ah[i], bh_[j], a, 0,0,0);
          a = __builtin_amdgcn_mfma_f32_16x16x32_bf16(al[i], bh_[j], a, 0,0,0);
          acc[i][jh*4+j] = a;
        }
      }
    }
  }
  __syncthreads();

  int mbase = m0 + w*64 + kg*4;
  #pragma unroll
  for (int jj=0;jj<8;jj++){
    int gn = n0 + jj*16 + lrow;
    float bias = bd[gn];
    #pragma unroll
    for (int i=0;i<4;i++){
      #pragma unroll
      for (int r=0;r<4;r++){
        int m = mbase + i*16 + r;
        size_t crow = (size_t)((m & 7)*SEQ + (m >> 3));
        C[crow*(size_t)VOC + gn] = acc[i][jj][r] + bias;
      }
    }
  }
}

// ---------- k_proj0: fallback (f32 W, 3-pass) — R13-proven ----------
__global__ __launch_bounds__(256) void k_proj0(
    const unsigned short* __restrict__ AH,
    const unsigned short* __restrict__ AL,
    const float* __restrict__ Wf,
    const float* __restrict__ bd,
    float* __restrict__ C)
{
  __shared__ unsigned short AsH[16*1024], AsL[16*1024];
  __shared__ unsigned short BsH[8*1024],  BsL[8*1024];
  int tid = threadIdx.x;
  int m0 = blockIdx.y*256, n0 = blockIdx.x*128;
  int w = tid >> 6, l = tid & 63;
  int lrow = l & 15, kg = l >> 4;

  f32x4 acc[4][8];
  #pragma unroll
  for (int i=0;i<4;i++){
    #pragma unroll
    for (int j=0;j<8;j++) acc[i][j] = (f32x4){0.f,0.f,0.f,0.f};
  }

  int rA = tid >> 3, fq = tid & 7;

  for (int kt=0; kt<32; ++kt){
    int k0 = kt*32;
    uint2 avh[8], avl[8];
    #pragma unroll
    for (int i=0;i<8;i++){
      size_t off = (size_t)(m0 + rA + 32*i)*1024 + k0 + fq*4;
      avh[i] = *(const uint2*)&AH[off];
      avl[i] = *(const uint2*)&AL[off];
    }
    float4 wvf[4];
    #pragma unroll
    for (int i=0;i<4;i++)
      wvf[i] = *(const float4*)(Wf + (size_t)(k0 + rA)*VOC + n0 + fq*4 + 32*i);
    __syncthreads();
    #pragma unroll
    for (int i=0;i<8;i++){
      int r = rA + 32*i;
      int base = (r >> 4)*1024 + ((fq >> 1)*16 + (r & 15))*8 + (fq & 1)*4;
      *(uint2*)&AsH[base] = avh[i];
      *(uint2*)&AsL[base] = avl[i];
    }
    #pragma unroll
    for (int i=0;i<4;i++){
      float xs[4] = {wvf[i].x, wvf[i].y, wvf[i].z, wvf[i].w};
      #pragma unroll
      for (int c=0;c<4;c++){
        int col = fq*4 + 32*i + c;
        int idx = (col >> 4)*1024 + ((rA >> 3)*16 + (col & 15))*8 + (rA & 7);
        unsigned short h = f2bf(xs[c]);
        BsH[idx] = h;
        BsL[idx] = f2bf(xs[c] - bf2f(h));
      }
    }
    __syncthreads();
    bf16x8 ah[4], al[4];
    #pragma unroll
    for (int i=0;i<4;i++){
      int fi = w*4 + i;
      ah[i] = *(const bf16x8*)&AsH[fi*1024 + l*8];
      al[i] = *(const bf16x8*)&AsL[fi*1024 + l*8];
    }
    #pragma unroll
    for (int jh=0;jh<2;jh++){
      bf16x8 bh_[4], bl_[4];
      #pragma unroll
      for (int j=0;j<4;j++){
        bh_[j] = *(const bf16x8*)&BsH[(jh*4+j)*1024 + l*8];
        bl_[j] = *(const bf16x8*)&BsL[(jh*4+j)*1024 + l*8];
      }
      #pragma unroll
      for (int i=0;i<4;i++){
        #pragma unroll
        for (int j=0;j<4;j++){
          f32x4 a = acc[i][jh*4+j];
          a = __builtin_amdgcn_mfma_f32_16x16x32_bf16(ah[i], bh_[j], a, 0,0,0);
          a = __builtin_amdgcn_mfma_f32_16x16x32_bf16(ah[i], bl_[j], a, 0,0,0);
          a = __builtin_amdgcn_mfma_f32_16x16x32_bf16(al[i], bh_[j], a, 0,0,0);
          acc[i][jh*4+j] = a;
        }
      }
    }
    __syncthreads();
  }

  int mbase = m0 + w*64 + kg*4;
  #pragma unroll
  for (int jj=0;jj<8;jj++){
    int gn = n0 + jj*16 + lrow;
    float bias = bd[gn];
    #pragma unroll
    for (int i=0;i<4;i++){
      #pragma unroll
      for (int r=0;r<4;r++){
        int m = mbase + i*16 + r;
        size_t crow = (size_t)((m & 7)*SEQ + (m >> 3));
        C[crow*(size_t)VOC + gn] = acc[i][jj][r] + bias;
      }
    }
  }
}

// ---------- fused 2-layer pipelined recurrence (R12/R13-proven, verbatim) ----------
__global__ __launch_bounds__(256) void k_rec2(
    const float* __restrict__ G,      // G0 [2048][4096], bias folded
    const float* __restrict__ Wh,     // [2][1024][4096]
    const float* __restrict__ Wx,     // [2][1024][4096]
    const float* __restrict__ bx1,    // bx + GATES
    const float* __restrict__ bh1,    // bh + GATES
    unsigned short* __restrict__ TopsH,  // [2048][1024] bf16 hi, row = s*8+b
    unsigned short* __restrict__ TopsL,  // bf16 lo
    unsigned* __restrict__ hbu,       // packed h [2 layers][2 parity][8][512]
    unsigned* __restrict__ flags)     // [256][16]
{
  extern __shared__ char ldsb[];
  unsigned short* A0 = (unsigned short*)ldsb;
  unsigned short* A1 = A0 + 16384;
  unsigned short* A2 = A1 + 16384;
  unsigned short* hB = A2 + 16384;
  float* Cx = (float*)(ldsb + 131072);
  int tid = threadIdx.x;
  int u0 = blockIdx.x*4;
  const int wv = tid >> 6, ln = tid & 63;
  const int fs0 = tid*16, fs1 = (tid+64)*16, fs2 = (tid+128)*16, fs3 = (tid+192)*16;

  {
    int m = tid >> 4, kseg = tid & 15;
    int col = (m >> 2)*1024 + u0 + (m & 3);
    const float* wsrc[3] = { Wh, Wx + (size_t)HID*GATES, Wh + (size_t)HID*GATES };
    unsigned short* Ad[3] = { A0, A1, A2 };
    for (int tgt=0; tgt<3; ++tgt){
      const float* s = wsrc[tgt] + col;
      #pragma unroll
      for (int run=0; run<8; ++run){
        int k0 = kseg*64 + run*8;
        int kt = k0 >> 5, kg = (k0 >> 3) & 3;
        bf16x8 v;
        #pragma unroll
        for (int e=0;e<8;e++) v[e] = (short)f2bf(s[(size_t)(k0+e)*GATES]);
        *(bf16x8*)&Ad[tgt][kt*512 + ((kg<<4)|m)*8] = v;
      }
    }
  }
  float b1r[4] = {0.f,0.f,0.f,0.f};
  if (tid >= 32 && tid < 64){
    int j = tid & 3;
    #pragma unroll
    for (int g=0;g<4;g++) b1r[g] = bx1[g*1024+u0+j] + bh1[g*1024+u0+j];
  }
  float creg = 0.0f;

  for (int p=0; p<=SEQ; ++p){
    const unsigned* h0b = hbu + (size_t)(p&1)*4096;
    const unsigned* h1b = hbu + 8192 + (size_t)((p+1)&1)*4096;
    {
      int colp = tid & 15, seg0 = tid >> 4;
      #pragma unroll
      for (int i=0;i<2;i++){
        int seg = seg0 + 16*i;
        const float* src = (const float*)(((colp < 8) ? h0b : h1b)
                                          + (colp & 7)*512 + seg*16);
        float4 r0,r1,r2,r3;
        asm volatile(
          "global_load_dwordx4 %0, %4, off sc0 sc1\n\t"
          "global_load_dwordx4 %1, %4, off offset:16 sc0 sc1\n\t"
          "global_load_dwordx4 %2, %4, off offset:32 sc0 sc1\n\t"
          "global_load_dwordx4 %3, %4, off offset:48 sc0 sc1\n\t"
          "s_waitcnt vmcnt(0)"
          : "=&v"(r0),"=&v"(r1),"=&v"(r2),"=&v"(r3)
          : "v"(src)
          : "memory");
        *(float4*)&hB[seg*512 + ((0<<4)|colp)*8] = r0;
        *(float4*)&hB[seg*512 + ((1<<4)|colp)*8] = r1;
        *(float4*)&hB[seg*512 + ((2<<4)|colp)*8] = r2;
        *(float4*)&hB[seg*512 + ((3<<4)|colp)*8] = r3;
      }
    }
    float gp0=0.f,gp1=0.f,gp2=0.f,gp3=0.f;
    if (tid < 32 && p < SEQ){
      const float* gp = G + ((size_t)p*8 + (tid>>2))*GATES + u0 + (tid&3);
      gp0 = gp[0]; gp1 = gp[1024]; gp2 = gp[2048]; gp3 = gp[3072];
    }
    __syncthreads();

    f32x4 C0 = {0.f,0.f,0.f,0.f}, C1 = {0.f,0.f,0.f,0.f}, C2 = {0.f,0.f,0.f,0.f};
    #pragma unroll
    for (int kti=0; kti<8; ++kti){
      int kt = wv + kti*4;
      bf16x8 bB = *(const bf16x8*)&hB[kt*512 + ln*8];
      bf16x8 a0 = *(const bf16x8*)&A0[kt*512 + ln*8];
      bf16x8 a1 = *(const bf16x8*)&A1[kt*512 + ln*8];
      bf16x8 a2 = *(const bf16x8*)&A2[kt*512 + ln*8];
      C0 = __builtin_amdgcn_mfma_f32_16x16x32_bf16(a0, bB, C0, 0,0,0);
      C1 = __builtin_amdgcn_mfma_f32_16x16x32_bf16(a1, bB, C1, 0,0,0);
      C2 = __builtin_amdgcn_mfma_f32_16x16x32_bf16(a2, bB, C2, 0,0,0);
    }
    {
      int cn = ln & 15, mb = (ln >> 4)*4;
      #pragma unroll
      for (int r=0;r<4;r++){
        Cx[((wv*3+0)*16 + mb+r)*17 + cn] = C0[r];
        Cx[((wv*3+1)*16 + mb+r)*17 + cn] = C1[r];
        Cx[((wv*3+2)*16 + mb+r)*17 + cn] = C2[r];
      }
    }
    __syncthreads();

    float hv = 0.f; bool pub = false; unsigned dstbase = 0;
    if (tid < 32){
      if (p < SEQ){
        int b = tid >> 2, j = tid & 3;
        float gv0=gp0, gv1=gp1, gv2=gp2, gv3=gp3;
        #pragma unroll
        for (int w=0;w<4;w++){
          gv0 += Cx[((w*3+0)*16 + 0*4+j)*17 + b];
          gv1 += Cx[((w*3+0)*16 + 1*4+j)*17 + b];
          gv2 += Cx[((w*3+0)*16 + 2*4+j)*17 + b];
          gv3 += Cx[((w*3+0)*16 + 3*4+j)*17 + b];
        }
        float iv = sigf(gv0), fv = sigf(gv1), ov = sigf(gv3), gg = tanhf_(gv2);
        creg = fv*creg + iv*gg;
        hv = ov * tanhf_(creg);
        pub = true; dstbase = ((unsigned)(p+1)&1u)*4096u;
      }
    } else if (tid < 64){
      if (p > 0){
        int b = (tid-32) >> 2, j = tid & 3;
        float gv0=b1r[0], gv1=b1r[1], gv2=b1r[2], gv3=b1r[3];
        #pragma unroll
        for (int w=0;w<4;w++){
          gv0 += Cx[((w*3+1)*16 + 0*4+j)*17 + b] + Cx[((w*3+2)*16 + 0*4+j)*17 + b+8];
          gv1 += Cx[((w*3+1)*16 + 1*4+j)*17 + b] + Cx[((w*3+2)*16 + 1*4+j)*17 + b+8];
          gv2 += Cx[((w*3+1)*16 + 2*4+j)*17 + b] + Cx[((w*3+2)*16 + 2*4+j)*17 + b+8];
          gv3 += Cx[((w*3+1)*16 + 3*4+j)*17 + b] + Cx[((w*3+2)*16 + 3*4+j)*17 + b+8];
        }
        float iv = sigf(gv0), fv = sigf(gv1), ov = sigf(gv3), gg = tanhf_(gv2);
        creg = fv*creg + iv*gg;
        hv = ov * tanhf_(creg);
        pub = true; dstbase = 8192u + ((unsigned)p&1u)*4096u;
        unsigned short hi = f2bf(hv);
        unsigned short lo = f2bf(hv - bf2f(hi));
        size_t off = ((size_t)(p-1)*8 + b)*HID + u0 + (tid&3);
        TopsH[off] = hi;
        TopsL[off] = lo;
      }
    }
    if (tid < 64){
      unsigned mybits = (unsigned)f2bf(hv);
      unsigned other  = (unsigned)__shfl_xor((int)mybits, 1);
      if (pub && ((tid & 1) == 0)){
        unsigned word = (mybits & 0xffffu) | (other << 16);
        int b = (tid & 31) >> 2;
        int widx = (u0 >> 1) + ((tid >> 1) & 1);
        (void)__hip_atomic_exchange(&hbu[dstbase + b*512 + widx], word,
                                    __ATOMIC_RELAXED, __HIP_MEMORY_SCOPE_AGENT);
      }
    }

    if (p < SEQ){
      if (tid < 64){
        if (tid == 0){
          asm volatile("s_waitcnt vmcnt(0)" ::: "memory");
          (void)__hip_atomic_exchange(&flags[blockIdx.x*16], (unsigned)(p+1),
                                      __ATOMIC_RELAXED, __HIP_MEMORY_SCOPE_AGENT);
        }
        unsigned tgt = (unsigned)(p+1);
        int spins = 0;
        for (;;){
          unsigned a = __hip_atomic_load(&flags[fs0], __ATOMIC_RELAXED, __HIP_MEMORY_SCOPE_AGENT);
          unsigned b = __hip_atomic_load(&flags[fs1], __ATOMIC_RELAXED, __HIP_MEMORY_SCOPE_AGENT);
          unsigned c = __hip_atomic_load(&flags[fs2], __ATOMIC_RELAXED, __HIP_MEMORY_SCOPE_AGENT);
          unsigned d = __hip_atomic_load(&flags[fs3], __ATOMIC_RELAXED, __HIP_MEMORY_SCOPE_AGENT);
          bool ok = (a >= tgt) && (b >= tgt) && (c >= tgt) && (d >= tgt);
          if (__all(ok)) break;
          __builtin_amdgcn_s_sleep(1);
          if (++spins > 150000){
            for (;;){
              unsigned a2 = __hip_atomic_load(&flags[fs0], __ATOMIC_ACQUIRE, __HIP_MEMORY_SCOPE_AGENT);
              unsigned b2 = __hip_atomic_load(&flags[fs1], __ATOMIC_ACQUIRE, __HIP_MEMORY_SCOPE_AGENT);
              unsigned c2 = __hip_atomic_load(&flags[fs2], __ATOMIC_ACQUIRE, __HIP_MEMORY_SCOPE_AGENT);
              unsigned d2 = __hip_atomic_load(&flags[fs3], __ATOMIC_ACQUIRE, __HIP_MEMORY_SCOPE_AGENT);
              bool ok2 = (a2 >= tgt) && (b2 >= tgt) && (c2 >= tgt) && (d2 >= tgt);
              if (__all(ok2)) break;
              __builtin_amdgcn_s_sleep(8);
              if (++spins > 8000000) break;   // wrong answer beats a hang
            }
            break;
          }
        }
      }
      __syncthreads();
    }
  }
}

extern "C" void kernel_launch(void* const* d_in, const int* in_sizes, int n_in,
                              void* d_out, int out_size, void* d_ws, size_t ws_size,
                              hipStream_t stream) {
  const int*   tokens = (const int*)d_in[0];
  const float* emb = (const float*)d_in[1];
  const float* Wx  = (const float*)d_in[2];
  const float* bx  = (const float*)d_in[3];
  const float* Wh  = (const float*)d_in[4];
  const float* bh  = (const float*)d_in[5];
  const float* Wd  = (const float*)d_in[6];
  const float* bd  = (const float*)d_in[7];
  float* out = (float*)d_out;
  float* ws  = (float*)d_ws;

  // ws layout (float offsets):
  //   G 0..8388608 | TopsH 8388608 | TopsL 9437184 | hbu 10485760 |
  //   flags 10502144 | WdH 10506240 .. 26890240 (u16 x 32.768M)
  float* G = ws;
  unsigned short* TopsH = (unsigned short*)(ws + (size_t)8388608);
  unsigned short* TopsL = (unsigned short*)(ws + (size_t)9437184);
  unsigned* hbu   = (unsigned*)(ws + (size_t)10485760);
  unsigned* flags = (unsigned*)(ws + (size_t)10502144);
  unsigned short* WdH = (unsigned short*)(ws + (size_t)10506240);
  const bool wpre = ws_size >= (size_t)26890240*4;

  (void)hipFuncSetAttribute((const void*)k_rec2,
        hipFuncAttributeMaxDynamicSharedMemorySize, 144128);

  k_init<<<32,256,0,stream>>>(flags, hbu);
  if (wpre)
    k_wconv<<<2048,256,0,stream>>>(Wd, WdH);

  // G0 = emb[tok] @ Wx0 + (bx0+bh0)   [split-bf16 MFMA]
  k_mfma<1,0><<<dim3(32,8),256,0,stream>>>(nullptr, Wx, bx, bh, tokens, emb, G, GATES);

  // fused pipelined recurrence: both layers, 257 phases
  k_rec2<<<256,256,144128,stream>>>(G, Wh, Wx, bx + GATES, bh + GATES,
                                    TopsH, TopsL, hbu, flags);

  // final projection
  if (wpre)
    k_proj1<<<dim3(250,8),256,0,stream>>>(TopsH, TopsL, WdH, bd, out);
  else
    k_proj0<<<dim3(250,8),256,0,stream>>>(TopsH, TopsL, Wd, bd, out);
}